// Round 7
// baseline (393.633 us; speedup 1.0000x reference)
//
#include <hip/hip_runtime.h>
#include <stdint.h>
#include <stddef.h>

#define IN_F 4096
#define OUT_F 4096

typedef int i32x4 __attribute__((ext_vector_type(4)));

// small cross-dispatch buffers live in device globals (no ws aliasing games)
__device__ float  g_alpha[IN_F];
__device__ double g_delta[IN_F];
__device__ float  g_scale[8192];

// ---------- helpers ----------

__device__ static inline void async16(const void* g, void* l) {
    __builtin_amdgcn_global_load_lds(
        (const __attribute__((address_space(1))) unsigned int*)g,
        (__attribute__((address_space(3))) unsigned int*)l,
        16, 0, 0);
}

__device__ static inline double wred_d(double v) {
#pragma unroll
    for (int o = 32; o > 0; o >>= 1) v += __shfl_down(v, o, 64);
    return v;
}

__device__ static inline int wred_i(int v) {
#pragma unroll
    for (int o = 32; o > 0; o >>= 1) v += __shfl_down(v, o, 64);
    return v;
}

__device__ static inline float wred_max(float v) {
#pragma unroll
    for (int o = 32; o > 0; o >>= 1) v = fmaxf(v, __shfl_down(v, o, 64));
    return v;
}

// ---------- D1: per-row stats only -> g_alpha, g_delta (FROZEN) ----------

__global__ __launch_bounds__(256) void rowstats_kernel(
    const float* __restrict__ w) {
    __shared__ double sh_s[4], sh_m[4];
    __shared__ int sh_c[4];
    const int row = blockIdx.x;
    const int t = threadIdx.x;
    const int lane = t & 63, wv = t >> 6;
    const float4* wr = (const float4*)(w + (size_t)row * OUT_F);

    float4 v[4];
    double s = 0.0;
#pragma unroll
    for (int it = 0; it < 4; ++it) {
        v[it] = wr[t + it * 256];
        s += (double)fabsf(v[it].x) + (double)fabsf(v[it].y) +
             (double)fabsf(v[it].z) + (double)fabsf(v[it].w);
    }
    double sw = wred_d(s);
    if (lane == 0) sh_s[wv] = sw;
    __syncthreads();
    const double delta = (sh_s[0] + sh_s[1] + sh_s[2] + sh_s[3]) *
                         (0.7 / (double)OUT_F);

    double ms = 0.0;
    int cnt = 0;
#pragma unroll
    for (int it = 0; it < 4; ++it) {
        float f[4] = {v[it].x, v[it].y, v[it].z, v[it].w};
#pragma unroll
        for (int j = 0; j < 4; ++j) {
            double a = (double)fabsf(f[j]);
            if (a > delta) { ms += a; ++cnt; }
        }
    }
    double msw = wred_d(ms);
    int cw = wred_i(cnt);
    if (lane == 0) { sh_m[wv] = msw; sh_c[wv] = cw; }
    __syncthreads();
    if (t == 0) {
        double mtot = sh_m[0] + sh_m[1] + sh_m[2] + sh_m[3];
        int ctot = sh_c[0] + sh_c[1] + sh_c[2] + sh_c[3];
        g_alpha[row] = (float)(mtot / (double)ctot);
        g_delta[row] = delta;
    }
}

// ---------- D2: fused {xquant | tern+transpose} (FROZEN) ----------

__global__ __launch_bounds__(256) void fused_tq(
    const float* __restrict__ w,
    const float* __restrict__ x,
    int8_t* __restrict__ Xq,
    int8_t* __restrict__ Tt,
    int nxq) {
    __shared__ __align__(16) unsigned int ldsb[128 * 33];  // 16.9 KB
    const int t = threadIdx.x;

    if ((int)blockIdx.x < nxq) {
        float* sh_mx = (float*)ldsb;
        const int row = blockIdx.x;
        const int lane = t & 63, wv = t >> 6;
        const float4* xr = (const float4*)(x + (size_t)row * IN_F);
        const float4* ar = (const float4*)g_alpha;

        float4 xs[4];
        float mx = 0.0f;
#pragma unroll
        for (int it = 0; it < 4; ++it) {
            float4 v = xr[t + it * 256];
            float4 a = ar[t + it * 256];
            v.x *= a.x; v.y *= a.y; v.z *= a.z; v.w *= a.w;
            xs[it] = v;
            mx = fmaxf(mx, fmaxf(fmaxf(fabsf(v.x), fabsf(v.y)),
                                 fmaxf(fabsf(v.z), fabsf(v.w))));
        }
        float mw = wred_max(mx);
        if (lane == 0) sh_mx[wv] = mw;
        __syncthreads();
        const float rmax = fmaxf(fmaxf(sh_mx[0], sh_mx[1]),
                                 fmaxf(sh_mx[2], sh_mx[3]));
        const float inv = (rmax > 0.0f) ? (127.0f / rmax) : 0.0f;

        unsigned int* qd = (unsigned int*)(Xq + (size_t)row * IN_F);
#pragma unroll
        for (int it = 0; it < 4; ++it) {
            float f[4] = {xs[it].x, xs[it].y, xs[it].z, xs[it].w};
            unsigned int u = 0;
#pragma unroll
            for (int j = 0; j < 4; ++j) {
                int q = __float2int_rn(f[j] * inv);
                u |= (unsigned int)(q & 0xff) << (j * 8);
            }
            qd[t + it * 256] = u;
        }
        if (t == 0) g_scale[row] = (rmax > 0.0f) ? (rmax / 127.0f) : 1.0f;
    } else {
        const int tt = blockIdx.x - nxq;
        const int i0 = (tt >> 5) * 128;  // IN
        const int j0 = (tt & 31) * 128;  // OUT
#pragma unroll
        for (int it = 0; it < 4; ++it) {
            int bb = it * 256 + t;
            int rg = bb >> 5;
            int cc = bb & 31;
            unsigned int col[4] = {0u, 0u, 0u, 0u};
#pragma unroll
            for (int k = 0; k < 4; ++k) {
                int irow = i0 + rg * 4 + k;
                float4 v = *(const float4*)(w + (size_t)irow * OUT_F + j0 + cc * 4);
                double d = g_delta[irow];
                float f[4] = {v.x, v.y, v.z, v.w};
#pragma unroll
                for (int j = 0; j < 4; ++j) {
                    int q = ((double)f[j] > d) ? 1 : (((double)f[j] < -d) ? -1 : 0);
                    col[j] |= (unsigned int)(q & 0xff) << (k * 8);
                }
            }
#pragma unroll
            for (int j = 0; j < 4; ++j)
                ldsb[(cc * 4 + j) * 33 + rg] = col[j];
        }
        __syncthreads();
#pragma unroll
        for (int it = 0; it < 4; ++it) {
            int idx = it * 256 + t;
            int rr = idx >> 3;
            int c2 = idx & 7;
            uint4 o;
            o.x = ldsb[rr * 33 + c2 * 4 + 0];
            o.y = ldsb[rr * 33 + c2 * 4 + 1];
            o.z = ldsb[rr * 33 + c2 * 4 + 2];
            o.w = ldsb[rr * 33 + c2 * 4 + 3];
            *(uint4*)(Tt + (size_t)(j0 + rr) * IN_F + i0 + c2 * 16) = o;
        }
    }
}

// ---------- D3: i8 MFMA GEMM, 256x256, BK=64, 64 KiB LDS -> 2 blocks/CU ----
// Occupancy fix: 128 KiB LDS allowed only 1 block/CU (2 waves/SIMD) -> matrix
// pipe idled at every barrier. BK=64 halves LDS to 64 KiB -> 2 blocks/CU.
// Swizzle for 64-B rows: chunk ^= (lm>>1)&3 -> uniform 2-way banking (free).
// (row>>1)&3 invariant across wm/wn/mi/ni offsets (all ≡0 mod 8).
// vmcnt audit (2 loads per STAGE): steady outstanding entering ph0 = 2
// (next-B). ph0 +2 (A1), ph1 +2 (B0) then vmcnt(2) drains next-B + A1 before
// ph2 reads them. Symmetric for ph2/ph3. Last iteration drains to 0.

#define GBARRIER() asm volatile("s_barrier" ::: "memory")

#define STAGE(G, GR0, TILE, LBASE)                                              \
    do {                                                                        \
        _Pragma("unroll")                                                       \
        for (int rr_ = 0; rr_ < 2; ++rr_) {                                     \
            const int L_ = rr_ * 512 + t;                                       \
            const int row_ = L_ >> 2;                                           \
            const int gch_ = (L_ & 3) ^ ((row_ >> 1) & 3);                      \
            async16((G) + (size_t)((GR0) + row_) * IN_F + (TILE) * 64 +         \
                        (gch_ << 4),                                            \
                    (LBASE) + (L_ << 4));                                       \
        }                                                                       \
    } while (0)

#define READ_A(BUF, MI0)                                                        \
    _Pragma("unroll")                                                           \
    for (int mi_ = 0; mi_ < 4; ++mi_)                                           \
        a[mi_] = *(const i32x4*)((BUF) + offA + ((MI0) + mi_) * 1024);

#define READ_B(BUF)                                                             \
    _Pragma("unroll")                                                           \
    for (int ni_ = 0; ni_ < 4; ++ni_)                                           \
        bB[ni_] = *(const i32x4*)((BUF) + offB + ni_ * 1024);

#define MFMA_Q(MI0)                                                             \
    do {                                                                        \
        __builtin_amdgcn_s_setprio(1);                                          \
        _Pragma("unroll")                                                       \
        for (int mi_ = 0; mi_ < 4; ++mi_) {                                     \
            _Pragma("unroll")                                                   \
            for (int ni_ = 0; ni_ < 4; ++ni_) {                                 \
                acc[(MI0) + mi_][ni_] =                                         \
                    __builtin_amdgcn_mfma_i32_16x16x64_i8(                      \
                        a[mi_], bB[ni_], acc[(MI0) + mi_][ni_], 0, 0, 0);       \
            }                                                                   \
        }                                                                       \
        __builtin_amdgcn_s_setprio(0);                                          \
    } while (0)

__global__ __launch_bounds__(512, 2) void gemm_i8_bk64(
    const int8_t* __restrict__ Xq,   // [M,K]
    const int8_t* __restrict__ Tq,   // [N,K]
    const float* __restrict__ bias,  // [N]
    float* __restrict__ out) {
    extern __shared__ __align__(16) int8_t lds[];  // 65536 B
    const int K = IN_F;
    const int NT = K / 64;    // 64 K-tiles
    const int NI = NT / 2;    // 32 iterations

    const int t = threadIdx.x;
    const int lane = t & 63;
    const int wave = t >> 6;
    const int lm = lane & 15;
    const int qh = lane >> 4;
    const int wm = (wave >> 2) << 7;
    const int wn = (wave & 3) << 6;

    const int nwg = gridDim.x;
    const int id = blockIdx.x;
    const int swz = (id & 7) * (nwg >> 3) + (id >> 3);
    const int m0 = (swz >> 4) << 8;
    const int n0 = (swz & 15) << 8;

    int8_t* const A0 = lds;               // 16 KB each
    int8_t* const B0 = lds + 16384;
    int8_t* const A1 = lds + 32768;
    int8_t* const B1 = lds + 49152;

    const int swz2 = (lm >> 1) & 3;
    const int offA = (wm + lm) * 64 + ((qh ^ swz2) << 4);
    const int offB = (wn + lm) * 64 + ((qh ^ swz2) << 4);

    i32x4 acc[8][4];
#pragma unroll
    for (int i = 0; i < 8; ++i)
#pragma unroll
        for (int j = 0; j < 4; ++j)
#pragma unroll
            for (int r = 0; r < 4; ++r) acc[i][j][r] = 0;

    i32x4 a[4], bB[4];

    // ---- prologue: A(0)->A0, B(0)->B0, B(1)->B1; leave B(1)'s 2 in flight
    STAGE(Xq, m0, 0, A0);
    STAGE(Tq, n0, 0, B0);
    STAGE(Tq, n0, 1, B1);
    asm volatile("s_waitcnt vmcnt(2)" ::: "memory");
    GBARRIER();

#pragma unroll 1
    for (int i = 0; i < NI; ++i) {
        const int kt = 2 * i;
        // -- phase 0: buf0 A-lo + B; stage A(kt+1)->A1
        READ_A(A0, 0);
        READ_B(B0);
        STAGE(Xq, m0, kt + 1, A1);
        MFMA_Q(0);
        GBARRIER();
        // -- phase 1: buf0 A-hi; stage B(kt+2)->B0; wait A1,B1 ready
        READ_A(A0, 4);
        if (kt + 2 < NT) STAGE(Tq, n0, kt + 2, B0);
        MFMA_Q(4);
        if (i + 1 < NI) asm volatile("s_waitcnt vmcnt(2)" ::: "memory");
        else            asm volatile("s_waitcnt vmcnt(0)" ::: "memory");
        GBARRIER();
        // -- phase 2: buf1 A-lo + B; stage A(kt+2)->A0
        READ_A(A1, 0);
        READ_B(B1);
        if (kt + 2 < NT) STAGE(Xq, m0, kt + 2, A0);
        MFMA_Q(0);
        GBARRIER();
        // -- phase 3: buf1 A-hi; stage B(kt+3)->B1; wait A0,B0 ready
        READ_A(A1, 4);
        if (kt + 3 < NT) STAGE(Tq, n0, kt + 3, B1);
        MFMA_Q(4);
        if (i + 1 < NI) asm volatile("s_waitcnt vmcnt(2)" ::: "memory");
        else            asm volatile("s_waitcnt vmcnt(0)" ::: "memory");
        GBARRIER();
    }

    // ---- epilogue: C/D layout col=lane&15, row=(lane>>4)*4+reg
    const int q4 = qh << 2;
#pragma unroll
    for (int mi = 0; mi < 8; ++mi) {
        float sc[4];
#pragma unroll
        for (int r = 0; r < 4; ++r) sc[r] = g_scale[m0 + wm + mi * 16 + q4 + r];
#pragma unroll
        for (int ni = 0; ni < 4; ++ni) {
            int col = n0 + wn + ni * 16 + lm;
            float b = bias[col];
#pragma unroll
            for (int r = 0; r < 4; ++r) {
                int row = m0 + wm + mi * 16 + q4 + r;
                out[(size_t)row * OUT_F + col] =
                    (float)acc[mi][ni][r] * sc[r] + b;
            }
        }
    }
}

// ---------- launch ----------

extern "C" void kernel_launch(void* const* d_in, const int* in_sizes, int n_in,
                              void* d_out, int out_size, void* d_ws, size_t ws_size,
                              hipStream_t stream) {
    const float* x = (const float*)d_in[0];
    const float* w = (const float*)d_in[1];
    const float* bias = (const float*)d_in[2];
    float* out = (float*)d_out;
    const int B = in_sizes[0] / IN_F;  // 8192

    // ws layout (48 MB):
    //   [0, 16M)    Tt [OUT][IN] i8
    //   [16M, 48M)  Xq [B][IN] i8
    // alpha/delta/scale live in __device__ globals (no aliasing).
    char* ws = (char*)d_ws;
    int8_t* Tt = (int8_t*)ws;
    int8_t* Xq = (int8_t*)(ws + (size_t)16777216);

    static int lds_set = 0;
    if (!lds_set) {
        hipFuncSetAttribute((const void*)gemm_i8_bk64,
                            hipFuncAttributeMaxDynamicSharedMemorySize, 65536);
        lds_set = 1;
    }

    rowstats_kernel<<<IN_F, 256, 0, stream>>>(w);
    fused_tq<<<B + (IN_F / 128) * (OUT_F / 128), 256, 0, stream>>>(w, x, Xq, Tt, B);
    const int nwg = (B / 256) * (OUT_F / 256);  // 512
    gemm_i8_bk64<<<dim3(nwg), dim3(512), 65536, stream>>>(Xq, Tt, bias, out);
}